// Round 4
// baseline (894.861 us; speedup 1.0000x reference)
//
#include <hip/hip_runtime.h>
#include <hip/hip_bf16.h>

// Problem constants (fixed by reference setup_inputs)
#define M_TOK 16384   // B*S = 8*2048
#define DK    4096    // D_IN
#define DN    4096    // D_OUT
#define NE    8       // experts
#define NR    16      // lora rank
#define ERC   128     // E*R
#define RAC   160     // padded router+A columns (8 + 128 + 24 pad)
#define NT_MAIN 128   // base K-tiles of 32
#define NT_ALL  132   // + 4 expert K-tiles

typedef __attribute__((ext_vector_type(8))) short bfrag;   // 8 bf16 (4 VGPRs)
typedef __attribute__((ext_vector_type(4))) float f32x4;   // MFMA acc

__device__ __forceinline__ unsigned short f2bf(float f) {
  unsigned u = __builtin_bit_cast(unsigned, f);
  unsigned rounding = 0x7FFFu + ((u >> 16) & 1u);
  u += rounding;
  return (unsigned short)(u >> 16);
}

__device__ __forceinline__ void load_lds16(const void* g, void* l) {
  __builtin_amdgcn_global_load_lds(
      (__attribute__((address_space(1))) void*)(g),
      (__attribute__((address_space(3))) void*)(l), 16, 0, 0);
}

// ---------- conversion kernels ----------
__global__ void k_cvt(const float* __restrict__ in, unsigned short* __restrict__ out, long n4) {
  long i = (long)blockIdx.x * blockDim.x + threadIdx.x;
  long stride = (long)gridDim.x * blockDim.x;
  for (; i < n4; i += stride) {
    float4 v = reinterpret_cast<const float4*>(in)[i];
    ushort4 o;
    o.x = f2bf(v.x); o.y = f2bf(v.y); o.z = f2bf(v.z); o.w = f2bf(v.w);
    reinterpret_cast<ushort4*>(out)[i] = o;
  }
}

// RA[c][k], c in [0,160): c<8 -> W_router[c][k]; 8<=c<136 -> lora_A[e][k][r]; pad 0
__global__ void k_build_ra(const float* __restrict__ Wr, const float* __restrict__ lA,
                           unsigned short* __restrict__ RA) {
  int idx = blockIdx.x * 256 + threadIdx.x;
  if (idx >= RAC * DK) return;
  int c = idx >> 12;          // /4096
  int k = idx & (DK - 1);
  float v = 0.f;
  if (c < NE) {
    v = Wr[c * DK + k];
  } else if (c < NE + ERC) {
    int er = c - NE;
    int e = er >> 4, r = er & 15;
    v = lA[((long)e * DK + k) * NR + r];
  }
  RA[idx] = f2bf(v);
}

// BT[n][kp] = lora_B[kp/16][kp%16][n]  -> [DN][128] bf16
__global__ void k_build_bt(const float* __restrict__ lB, unsigned short* __restrict__ BT) {
  int idx = blockIdx.x * 256 + threadIdx.x;
  if (idx >= DN * ERC) return;
  int n = idx >> 7;
  int kp = idx & 127;
  BT[idx] = f2bf(lB[(long)kp * DN + n]);
}

// ---------- small GEMM: H[t][c] = sum_k Xb[t][k]*RA[c][k], c in [0,160) ----------
__global__ __launch_bounds__(256, 2)
void k_gemm_small(const unsigned short* __restrict__ X, const unsigned short* __restrict__ RA,
                  float* __restrict__ H) {
  __shared__ unsigned short At[64 * 64];
  __shared__ unsigned short Bt[RAC * 64];
  int m0 = blockIdx.x * 64;
  int tid = threadIdx.x;
  int lane = tid & 63, wid = tid >> 6;
  int wr = wid >> 1, wc = wid & 1;      // 2x2 waves; wave tile 32 x 80
  int l16 = lane & 15, lhi = lane >> 4;
  f32x4 acc[2][5] = {};
  int byteoff = tid * 16;
  for (int k0 = 0; k0 < DK; k0 += 64) {
#pragma unroll
    for (int r = 0; r < 2; r++) {
      int off = r * 4096 + byteoff;
      int row = off >> 7, colb = off & 127;
      load_lds16((const char*)X + ((long)(m0 + row) * DK + k0) * 2 + colb, (char*)At + off);
    }
#pragma unroll
    for (int r = 0; r < 5; r++) {
      int off = r * 4096 + byteoff;
      int row = off >> 7, colb = off & 127;
      load_lds16((const char*)RA + ((long)row * DK + k0) * 2 + colb, (char*)Bt + off);
    }
    __syncthreads();
#pragma unroll
    for (int kk = 0; kk < 2; kk++) {
      bfrag a[2], b[5];
#pragma unroll
      for (int m = 0; m < 2; m++)
        a[m] = *(const bfrag*)&At[(wr * 32 + m * 16 + l16) * 64 + kk * 32 + lhi * 8];
#pragma unroll
      for (int n = 0; n < 5; n++)
        b[n] = *(const bfrag*)&Bt[(wc * 80 + n * 16 + l16) * 64 + kk * 32 + lhi * 8];
#pragma unroll
      for (int m = 0; m < 2; m++)
#pragma unroll
        for (int n = 0; n < 5; n++)
          acc[m][n] = __builtin_amdgcn_mfma_f32_16x16x32_bf16(a[m], b[n], acc[m][n], 0, 0, 0);
    }
    __syncthreads();
  }
#pragma unroll
  for (int m = 0; m < 2; m++)
#pragma unroll
    for (int n = 0; n < 5; n++) {
      int col = wc * 80 + n * 16 + l16;
      int row = m0 + wr * 32 + m * 16 + lhi * 4;
#pragma unroll
      for (int j = 0; j < 4; j++)
        H[(long)(row + j) * RAC + col] = acc[m][n][j];
    }
}

// ---------- sparsemax + weight application ----------
__global__ void k_router(const float* __restrict__ H, const float* __restrict__ b_router,
                         unsigned short* __restrict__ G) {
  int t = blockIdx.x * blockDim.x + threadIdx.x;
  if (t >= M_TOK) return;
  const float* row = H + (long)t * RAC;
  float z[NE], zs[NE];
#pragma unroll
  for (int e = 0; e < NE; e++) { z[e] = row[e] + b_router[e]; zs[e] = z[e]; }
#pragma unroll
  for (int i = 1; i < NE; i++) {
    float key = zs[i];
    int j = i - 1;
    while (j >= 0 && zs[j] < key) { zs[j + 1] = zs[j]; j--; }
    zs[j + 1] = key;
  }
  float cums[NE];
  float cum = 0.f;
#pragma unroll
  for (int j = 0; j < NE; j++) { cum += zs[j]; cums[j] = cum; }
  int kz = 0;
#pragma unroll
  for (int j = 0; j < NE; j++)
    if (1.f + (float)(j + 1) * zs[j] > cums[j]) kz = j + 1;
  float tau = (cums[kz - 1] - 1.f) / (float)kz;
#pragma unroll
  for (int e = 0; e < NE; e++) {
    float we = fmaxf(z[e] - tau, 0.f);
#pragma unroll
    for (int r = 0; r < NR; r++)
      G[(long)t * ERC + e * NR + r] = f2bf(we * row[NE + e * NR + r]);
  }
}

// ---------- main GEMM: 256x256 tile, BK=32, 4-deep ring, counted vmcnt ----------
// out = Xb @ Wb^T + bias + G @ BT^T, fused as 128 + 4 K-tiles of 32.
// T2 swizzle (rule #21 both-sides): LDS row = 64B = 4 slots of 16B; source slot
// pre-permuted by ((tid&3)^((tid>>3)&3)); read slot = lhi ^ ((l16>>1)&3).
// Register fragment double-buffer: tile t+1's bfr/afr_lo are ds_read during
// tile t's MFMA cluster (static 2-set swap, rule #20); afr_hi read JIT.
struct KtArgs {
  const unsigned short *pXA0, *pXA1, *pWB0, *pWB1, *pGA0, *pGA1, *pTB0, *pTB1;
  int soffA0, soffA1, soffB0, soffB1;   // element offsets within a ring slot
  int wr, wc, l16, swslot;              // swslot in shorts
};

template<int VMW, bool STAGE, bool READF>
__device__ __forceinline__ void ktile_body(int t, unsigned short* lds, const KtArgs& A,
                                           f32x4 (&acc)[8][4],
                                           bfrag (&bc)[4], bfrag (&ac)[4],   // current (loaded)
                                           bfrag (&bn)[4], bfrag (&an)[4]) { // next (fill here)
  // own stage(t+1) complete, THEN barrier => all waves' stage(t+1) visible.
  if constexpr (VMW == 4) asm volatile("s_waitcnt vmcnt(4)\n\ts_barrier" ::: "memory");
  else                    asm volatile("s_waitcnt vmcnt(0)\n\ts_barrier" ::: "memory");

  if constexpr (STAGE) {
    int u = t + 3;
    unsigned short* d = lds + (u & 3) * 16384;
    if (u < NT_MAIN) {
      load_lds16(A.pXA0 + (long)u * 32, d + A.soffA0);
      load_lds16(A.pXA1 + (long)u * 32, d + A.soffA1);
      load_lds16(A.pWB0 + (long)u * 32, d + A.soffB0);
      load_lds16(A.pWB1 + (long)u * 32, d + A.soffB1);
    } else {
      long v = u - NT_MAIN;
      load_lds16(A.pGA0 + v * 32, d + A.soffA0);
      load_lds16(A.pGA1 + v * 32, d + A.soffA1);
      load_lds16(A.pTB0 + v * 32, d + A.soffB0);
      load_lds16(A.pTB1 + v * 32, d + A.soffB1);
    }
  }

  unsigned short* s = lds + (t & 3) * 16384;
  // JIT read of this tile's A-hi fragments (waited before the hi-MFMA cluster)
  bfrag ah[4];
#pragma unroll
  for (int m = 0; m < 4; m++)
    ah[m] = *(const bfrag*)&s[(A.wr * 128 + 64 + m * 16 + A.l16) * 32 + A.swslot];
  // prefetch next tile's fragments into the alternate register set
  if constexpr (READF) {
    unsigned short* sn = lds + ((t + 1) & 3) * 16384;
#pragma unroll
    for (int n = 0; n < 4; n++)
      bn[n] = *(const bfrag*)&sn[8192 + (A.wc * 64 + n * 16 + A.l16) * 32 + A.swslot];
#pragma unroll
    for (int m = 0; m < 4; m++)
      an[m] = *(const bfrag*)&sn[(A.wr * 128 + m * 16 + A.l16) * 32 + A.swslot];
  }
  // lo cluster: deps (ac, bc) were read last tile -> no LDS wait needed here
  __builtin_amdgcn_s_setprio(1);
#pragma unroll
  for (int m = 0; m < 4; m++)
#pragma unroll
    for (int n = 0; n < 4; n++)
      acc[m][n] = __builtin_amdgcn_mfma_f32_16x16x32_bf16(ac[m], bc[n], acc[m][n], 0, 0, 0);
  __builtin_amdgcn_s_setprio(0);
  // hi cluster: waits (counted lgkm) for ah only
  __builtin_amdgcn_s_setprio(1);
#pragma unroll
  for (int m = 0; m < 4; m++)
#pragma unroll
    for (int n = 0; n < 4; n++)
      acc[4 + m][n] = __builtin_amdgcn_mfma_f32_16x16x32_bf16(ah[m], bc[n], acc[4 + m][n], 0, 0, 0);
  __builtin_amdgcn_s_setprio(0);
}

__global__ __launch_bounds__(512, 2)
void k_gemm_main(const unsigned short* __restrict__ X, const unsigned short* __restrict__ W,
                 const unsigned short* __restrict__ G, const unsigned short* __restrict__ BT,
                 const float* __restrict__ bias, float* __restrict__ out) {
  // 4 ring slots x (A[256][32] + B[256][32]) bf16 = 4 x 32 KiB = 128 KiB
  __shared__ unsigned short lds[4 * 16384];
  int bid = blockIdx.x;
  // XCD-aware swizzle: 1024 workgroups, 8 XCDs -> contiguous chunks of 128 per XCD
  int swz = (bid & 7) * 128 + (bid >> 3);
  int bm = swz >> 4, bn = swz & 15;
  int m0 = bm * 256, n0 = bn * 256;
  int tid = threadIdx.x;
  int lane = tid & 63, wid = tid >> 6;

  KtArgs A;
  A.wr = wid >> 2; A.wc = wid & 3;      // 2x4 waves; wave tile 128 x 64
  A.l16 = lane & 15;
  int lhi = lane >> 4;
  A.swslot = (lhi ^ ((A.l16 >> 1) & 3)) * 8;      // read-side swizzle (shorts)
  // staging: thread tid owns LDS (row=tid>>2, slot=tid&3); source slot pre-swizzled
  int r0 = tid >> 2;
  int c8 = (((tid & 3) ^ ((tid >> 3) & 3)) * 8);  // swizzled source column (shorts)
  A.pXA0 = X + (long)(m0 + r0) * DK + c8;
  A.pXA1 = X + (long)(m0 + 128 + r0) * DK + c8;
  A.pWB0 = W + (long)(n0 + r0) * DK + c8;
  A.pWB1 = W + (long)(n0 + 128 + r0) * DK + c8;
  A.pGA0 = G + (long)(m0 + r0) * ERC + c8;
  A.pGA1 = G + (long)(m0 + 128 + r0) * ERC + c8;
  A.pTB0 = BT + (long)(n0 + r0) * ERC + c8;
  A.pTB1 = BT + (long)(n0 + 128 + r0) * ERC + c8;
  A.soffA0 = tid * 8;
  A.soffA1 = 4096 + tid * 8;
  A.soffB0 = 8192 + tid * 8;
  A.soffB1 = 12288 + tid * 8;

  f32x4 acc[8][4] = {};

  // prologue: stage tiles 0,1,2 (all base-path)
#pragma unroll
  for (int u = 0; u < 3; u++) {
    unsigned short* d = lds + u * 16384;
    load_lds16(A.pXA0 + (long)u * 32, d + A.soffA0);
    load_lds16(A.pXA1 + (long)u * 32, d + A.soffA1);
    load_lds16(A.pWB0 + (long)u * 32, d + A.soffB0);
    load_lds16(A.pWB1 + (long)u * 32, d + A.soffB1);
  }
  // wait own stage(0), then barrier -> everyone's stage(0) visible; read frags(0)
  asm volatile("s_waitcnt vmcnt(8)\n\ts_barrier" ::: "memory");
  bfrag b0[4], a0[4], b1[4], a1[4];
#pragma unroll
  for (int n = 0; n < 4; n++)
    b0[n] = *(const bfrag*)&lds[8192 + (A.wc * 64 + n * 16 + A.l16) * 32 + A.swslot];
#pragma unroll
  for (int m = 0; m < 4; m++)
    a0[m] = *(const bfrag*)&lds[(A.wr * 128 + m * 16 + A.l16) * 32 + A.swslot];

  for (int tt = 0; tt < 128; tt += 2) {
    ktile_body<4, true, true>(tt,     lds, A, acc, b0, a0, b1, a1);
    ktile_body<4, true, true>(tt + 1, lds, A, acc, b1, a1, b0, a0);
  }
  ktile_body<4, true,  true >(128, lds, A, acc, b0, a0, b1, a1);
  ktile_body<4, false, true >(129, lds, A, acc, b1, a1, b0, a0);
  ktile_body<0, false, true >(130, lds, A, acc, b0, a0, b1, a1);
  ktile_body<0, false, false>(131, lds, A, acc, b1, a1, b0, a0);

  // epilogue: bias + f32 store
#pragma unroll
  for (int n = 0; n < 4; n++) {
    int col = n0 + A.wc * 64 + n * 16 + A.l16;
    float bv = bias[col];
#pragma unroll
    for (int m = 0; m < 8; m++) {
      int row = m0 + A.wr * 128 + m * 16 + lhi * 4;
#pragma unroll
      for (int j = 0; j < 4; j++)
        out[(long)(row + j) * DN + col] = acc[m][n][j] + bv;
    }
  }
}

extern "C" void kernel_launch(void* const* d_in, const int* in_sizes, int n_in,
                              void* d_out, int out_size, void* d_ws, size_t ws_size,
                              hipStream_t stream) {
  const float* x        = (const float*)d_in[0];
  const float* W_base   = (const float*)d_in[1];
  const float* b_base   = (const float*)d_in[2];
  const float* W_router = (const float*)d_in[3];
  const float* b_router = (const float*)d_in[4];
  const float* lora_A   = (const float*)d_in[5];
  const float* lora_B   = (const float*)d_in[6];
  float* out = (float*)d_out;

  char* ws = (char*)d_ws;
  unsigned short* Xb = (unsigned short*)ws;                       // 134217728 B
  unsigned short* Wb = (unsigned short*)(ws + 134217728L);        // 33554432 B
  unsigned short* RA = (unsigned short*)(ws + 167772160L);        // 1310720 B
  unsigned short* BT = (unsigned short*)(ws + 169082880L);        // 1048576 B
  float*          H  = (float*)(ws + 170131456L);                 // 10485760 B
  unsigned short* G  = (unsigned short*)(ws + 180617216L);        // 4194304 B

  hipLaunchKernelGGL(k_cvt, dim3(2048), dim3(256), 0, stream, x, Xb, (long)M_TOK * DK / 4);
  hipLaunchKernelGGL(k_cvt, dim3(2048), dim3(256), 0, stream, W_base, Wb, (long)DN * DK / 4);
  hipLaunchKernelGGL(k_build_ra, dim3((RAC * DK + 255) / 256), dim3(256), 0, stream,
                     W_router, lora_A, RA);
  hipLaunchKernelGGL(k_build_bt, dim3((DN * ERC + 255) / 256), dim3(256), 0, stream, lora_B, BT);
  hipLaunchKernelGGL(k_gemm_small, dim3(M_TOK / 64), dim3(256), 0, stream, Xb, RA, H);
  hipLaunchKernelGGL(k_router, dim3(M_TOK / 256), dim3(256), 0, stream, H, b_router, G);
  hipLaunchKernelGGL(k_gemm_main, dim3((M_TOK / 256) * (DN / 256)), dim3(512), 0, stream,
                     Xb, Wb, G, BT, b_base, out);
}

// Round 5
// 709.497 us; speedup vs baseline: 1.2613x; 1.2613x over previous
//
#include <hip/hip_runtime.h>
#include <hip/hip_bf16.h>

// Problem constants (fixed by reference setup_inputs)
#define M_TOK 16384   // B*S = 8*2048
#define DK    4096    // D_IN
#define DN    4096    // D_OUT
#define NE    8       // experts
#define NR    16      // lora rank
#define ERC   128     // E*R
#define RAC   160     // padded router+A columns (8 + 128 + 24 pad)
#define NT_MAIN 128   // base K-tiles of 32
#define NT_ALL  132   // + 4 expert K-tiles

typedef __attribute__((ext_vector_type(8))) short bfrag;   // 8 bf16 (4 VGPRs)
typedef __attribute__((ext_vector_type(4))) float f32x4;   // MFMA acc

__device__ __forceinline__ unsigned short f2bf(float f) {
  unsigned u = __builtin_bit_cast(unsigned, f);
  unsigned rounding = 0x7FFFu + ((u >> 16) & 1u);
  u += rounding;
  return (unsigned short)(u >> 16);
}

__device__ __forceinline__ void load_lds16(const void* g, void* l) {
  __builtin_amdgcn_global_load_lds(
      (__attribute__((address_space(1))) void*)(g),
      (__attribute__((address_space(3))) void*)(l), 16, 0, 0);
}

// ---------- conversion kernels ----------
__global__ void k_cvt(const float* __restrict__ in, unsigned short* __restrict__ out, long n4) {
  long i = (long)blockIdx.x * blockDim.x + threadIdx.x;
  long stride = (long)gridDim.x * blockDim.x;
  for (; i < n4; i += stride) {
    float4 v = reinterpret_cast<const float4*>(in)[i];
    ushort4 o;
    o.x = f2bf(v.x); o.y = f2bf(v.y); o.z = f2bf(v.z); o.w = f2bf(v.w);
    reinterpret_cast<ushort4*>(out)[i] = o;
  }
}

// RA[c][k], c in [0,160): c<8 -> W_router[c][k]; 8<=c<136 -> lora_A[e][k][r]; pad 0
__global__ void k_build_ra(const float* __restrict__ Wr, const float* __restrict__ lA,
                           unsigned short* __restrict__ RA) {
  int idx = blockIdx.x * 256 + threadIdx.x;
  if (idx >= RAC * DK) return;
  int c = idx >> 12;          // /4096
  int k = idx & (DK - 1);
  float v = 0.f;
  if (c < NE) {
    v = Wr[c * DK + k];
  } else if (c < NE + ERC) {
    int er = c - NE;
    int e = er >> 4, r = er & 15;
    v = lA[((long)e * DK + k) * NR + r];
  }
  RA[idx] = f2bf(v);
}

// BT[n][kp] = lora_B[kp/16][kp%16][n]  -> [DN][128] bf16
__global__ void k_build_bt(const float* __restrict__ lB, unsigned short* __restrict__ BT) {
  int idx = blockIdx.x * 256 + threadIdx.x;
  if (idx >= DN * ERC) return;
  int n = idx >> 7;
  int kp = idx & 127;
  BT[idx] = f2bf(lB[(long)kp * DN + n]);
}

// ---------- small GEMM: H[t][c] = sum_k Xb[t][k]*RA[c][k], c in [0,160) ----------
__global__ __launch_bounds__(256, 2)
void k_gemm_small(const unsigned short* __restrict__ X, const unsigned short* __restrict__ RA,
                  float* __restrict__ H) {
  __shared__ unsigned short At[64 * 64];
  __shared__ unsigned short Bt[RAC * 64];
  int m0 = blockIdx.x * 64;
  int tid = threadIdx.x;
  int lane = tid & 63, wid = tid >> 6;
  int wr = wid >> 1, wc = wid & 1;      // 2x2 waves; wave tile 32 x 80
  int l16 = lane & 15, lhi = lane >> 4;
  f32x4 acc[2][5] = {};
  int byteoff = tid * 16;
  for (int k0 = 0; k0 < DK; k0 += 64) {
#pragma unroll
    for (int r = 0; r < 2; r++) {
      int off = r * 4096 + byteoff;
      int row = off >> 7, colb = off & 127;
      load_lds16((const char*)X + ((long)(m0 + row) * DK + k0) * 2 + colb, (char*)At + off);
    }
#pragma unroll
    for (int r = 0; r < 5; r++) {
      int off = r * 4096 + byteoff;
      int row = off >> 7, colb = off & 127;
      load_lds16((const char*)RA + ((long)row * DK + k0) * 2 + colb, (char*)Bt + off);
    }
    __syncthreads();
#pragma unroll
    for (int kk = 0; kk < 2; kk++) {
      bfrag a[2], b[5];
#pragma unroll
      for (int m = 0; m < 2; m++)
        a[m] = *(const bfrag*)&At[(wr * 32 + m * 16 + l16) * 64 + kk * 32 + lhi * 8];
#pragma unroll
      for (int n = 0; n < 5; n++)
        b[n] = *(const bfrag*)&Bt[(wc * 80 + n * 16 + l16) * 64 + kk * 32 + lhi * 8];
#pragma unroll
      for (int m = 0; m < 2; m++)
#pragma unroll
        for (int n = 0; n < 5; n++)
          acc[m][n] = __builtin_amdgcn_mfma_f32_16x16x32_bf16(a[m], b[n], acc[m][n], 0, 0, 0);
    }
    __syncthreads();
  }
#pragma unroll
  for (int m = 0; m < 2; m++)
#pragma unroll
    for (int n = 0; n < 5; n++) {
      int col = wc * 80 + n * 16 + l16;
      int row = m0 + wr * 32 + m * 16 + lhi * 4;
#pragma unroll
      for (int j = 0; j < 4; j++)
        H[(long)(row + j) * RAC + col] = acc[m][n][j];
    }
}

// ---------- sparsemax + weight application ----------
__global__ void k_router(const float* __restrict__ H, const float* __restrict__ b_router,
                         unsigned short* __restrict__ G) {
  int t = blockIdx.x * blockDim.x + threadIdx.x;
  if (t >= M_TOK) return;
  const float* row = H + (long)t * RAC;
  float z[NE], zs[NE];
#pragma unroll
  for (int e = 0; e < NE; e++) { z[e] = row[e] + b_router[e]; zs[e] = z[e]; }
#pragma unroll
  for (int i = 1; i < NE; i++) {
    float key = zs[i];
    int j = i - 1;
    while (j >= 0 && zs[j] < key) { zs[j + 1] = zs[j]; j--; }
    zs[j + 1] = key;
  }
  float cums[NE];
  float cum = 0.f;
#pragma unroll
  for (int j = 0; j < NE; j++) { cum += zs[j]; cums[j] = cum; }
  int kz = 0;
#pragma unroll
  for (int j = 0; j < NE; j++)
    if (1.f + (float)(j + 1) * zs[j] > cums[j]) kz = j + 1;
  float tau = (cums[kz - 1] - 1.f) / (float)kz;
#pragma unroll
  for (int e = 0; e < NE; e++) {
    float we = fmaxf(z[e] - tau, 0.f);
#pragma unroll
    for (int r = 0; r < NR; r++)
      G[(long)t * ERC + e * NR + r] = f2bf(we * row[NE + e * NR + r]);
  }
}

// ---------- main GEMM: 256x256 tile, BK=32, 4-deep ring, m201 phase rhythm ----
// out = Xb @ Wb^T + bias + G @ BT^T, fused as 128 + 4 K-tiles of 32.
// Per phase: {issue ds_reads -> issue stage -> s_barrier -> lgkmcnt(0) ->
// setprio(1) 16xMFMA setprio(0)}; boundary vmcnt(8)+barrier once per K-tile
// (counted: stages for t+2,t+3 are the 8 newest outstanding -> certifies t+1).
// LDS drain hides in barrier-arrival skew + other waves' MFMA windows.
// T2 swizzle (rule #21 both-sides): source slot pre-permuted by
// ((tid&3)^((tid>>3)&3)); read slot = lhi ^ ((l16>>1)&3). Conflict-free.
struct KtArgs {
  const unsigned short *pXA0, *pXA1, *pWB0, *pWB1, *pGA0, *pGA1, *pTB0, *pTB1;
  int soffA0, soffA1, soffB0, soffB1;   // element offsets within a ring slot
  int wr, wc, l16, swslot;              // swslot in shorts
};

template<bool STAGE, int VMB>
__device__ __forceinline__ void ktile_body(int t, unsigned short* lds, const KtArgs& A,
                                           f32x4 (&acc)[8][4]) {
  unsigned short* s = lds + (t & 3) * 16384;
  bfrag bfr[4], al[4], ah[4];
  // ---- phase 0: issue reads (B-frags + A-lo), issue A-stage(t+3) ----
#pragma unroll
  for (int n = 0; n < 4; n++)
    bfr[n] = *(const bfrag*)&s[8192 + (A.wc * 64 + n * 16 + A.l16) * 32 + A.swslot];
#pragma unroll
  for (int m = 0; m < 4; m++)
    al[m] = *(const bfrag*)&s[(A.wr * 128 + m * 16 + A.l16) * 32 + A.swslot];
  if constexpr (STAGE) {
    int u = t + 3;
    unsigned short* d = lds + (u & 3) * 16384;
    if (u < NT_MAIN) {
      load_lds16(A.pXA0 + (long)u * 32, d + A.soffA0);
      load_lds16(A.pXA1 + (long)u * 32, d + A.soffA1);
    } else {
      long v = u - NT_MAIN;
      load_lds16(A.pGA0 + v * 32, d + A.soffA0);
      load_lds16(A.pGA1 + v * 32, d + A.soffA1);
    }
  }
  // barrier first (arrival skew overlaps LDS drain), then cheap lgkm0
  asm volatile("s_barrier\n\ts_waitcnt lgkmcnt(0)" ::: "memory");
  __builtin_amdgcn_sched_barrier(0);            // rule #18: pin MFMA after wait
  __builtin_amdgcn_s_setprio(1);
#pragma unroll
  for (int m = 0; m < 4; m++)
#pragma unroll
    for (int n = 0; n < 4; n++)
      acc[m][n] = __builtin_amdgcn_mfma_f32_16x16x32_bf16(al[m], bfr[n], acc[m][n], 0, 0, 0);
  __builtin_amdgcn_s_setprio(0);
  // ---- phase 1: issue reads (A-hi), issue B-stage(t+3) ----
#pragma unroll
  for (int m = 0; m < 4; m++)
    ah[m] = *(const bfrag*)&s[(A.wr * 128 + 64 + m * 16 + A.l16) * 32 + A.swslot];
  if constexpr (STAGE) {
    int u = t + 3;
    unsigned short* d = lds + (u & 3) * 16384;
    if (u < NT_MAIN) {
      load_lds16(A.pWB0 + (long)u * 32, d + A.soffB0);
      load_lds16(A.pWB1 + (long)u * 32, d + A.soffB1);
    } else {
      long v = u - NT_MAIN;
      load_lds16(A.pTB0 + v * 32, d + A.soffB0);
      load_lds16(A.pTB1 + v * 32, d + A.soffB1);
    }
  }
  asm volatile("s_barrier\n\ts_waitcnt lgkmcnt(0)" ::: "memory");
  __builtin_amdgcn_sched_barrier(0);
  __builtin_amdgcn_s_setprio(1);
#pragma unroll
  for (int m = 0; m < 4; m++)
#pragma unroll
    for (int n = 0; n < 4; n++)
      acc[4 + m][n] = __builtin_amdgcn_mfma_f32_16x16x32_bf16(ah[m], bfr[n], acc[4 + m][n], 0, 0, 0);
  __builtin_amdgcn_s_setprio(0);
  // ---- boundary: certify slot t+1 for next body's pre-barrier reads ----
  if constexpr (VMB == 8)      asm volatile("s_waitcnt vmcnt(8)\n\ts_barrier" ::: "memory");
  else if constexpr (VMB == 4) asm volatile("s_waitcnt vmcnt(4)\n\ts_barrier" ::: "memory");
  else if constexpr (VMB == 0) asm volatile("s_waitcnt vmcnt(0)\n\ts_barrier" ::: "memory");
  // VMB < 0: last tile, no boundary needed
}

__global__ __launch_bounds__(512, 2)
void k_gemm_main(const unsigned short* __restrict__ X, const unsigned short* __restrict__ W,
                 const unsigned short* __restrict__ G, const unsigned short* __restrict__ BT,
                 const float* __restrict__ bias, float* __restrict__ out) {
  // 4 ring slots x (A[256][32] + B[256][32]) bf16 = 4 x 32 KiB = 128 KiB
  __shared__ unsigned short lds[4 * 16384];
  int bid = blockIdx.x;
  // XCD-aware swizzle: 1024 workgroups, 8 XCDs -> contiguous chunks of 128 per XCD
  int swz = (bid & 7) * 128 + (bid >> 3);
  int bm = swz >> 4, bn = swz & 15;
  int m0 = bm * 256, n0 = bn * 256;
  int tid = threadIdx.x;
  int lane = tid & 63, wid = tid >> 6;

  KtArgs A;
  A.wr = wid >> 2; A.wc = wid & 3;      // 2x4 waves; wave tile 128 x 64
  A.l16 = lane & 15;
  int lhi = lane >> 4;
  A.swslot = (lhi ^ ((A.l16 >> 1) & 3)) * 8;      // read-side swizzle (shorts)
  // staging: thread tid owns LDS (row=tid>>2, slot=tid&3); source slot pre-swizzled
  int r0 = tid >> 2;
  int c8 = (((tid & 3) ^ ((tid >> 3) & 3)) * 8);  // swizzled source column (shorts)
  A.pXA0 = X + (long)(m0 + r0) * DK + c8;
  A.pXA1 = X + (long)(m0 + 128 + r0) * DK + c8;
  A.pWB0 = W + (long)(n0 + r0) * DK + c8;
  A.pWB1 = W + (long)(n0 + 128 + r0) * DK + c8;
  A.pGA0 = G + (long)(m0 + r0) * ERC + c8;
  A.pGA1 = G + (long)(m0 + 128 + r0) * ERC + c8;
  A.pTB0 = BT + (long)(n0 + r0) * ERC + c8;
  A.pTB1 = BT + (long)(n0 + 128 + r0) * ERC + c8;
  A.soffA0 = tid * 8;
  A.soffA1 = 4096 + tid * 8;
  A.soffB0 = 8192 + tid * 8;
  A.soffB1 = 12288 + tid * 8;

  f32x4 acc[8][4] = {};

  // prologue: stage tiles 0,1,2 (all base-path); certify slot 0
#pragma unroll
  for (int u = 0; u < 3; u++) {
    unsigned short* d = lds + u * 16384;
    load_lds16(A.pXA0 + (long)u * 32, d + A.soffA0);
    load_lds16(A.pXA1 + (long)u * 32, d + A.soffA1);
    load_lds16(A.pWB0 + (long)u * 32, d + A.soffB0);
    load_lds16(A.pWB1 + (long)u * 32, d + A.soffB1);
  }
  asm volatile("s_waitcnt vmcnt(8)\n\ts_barrier" ::: "memory");

  for (int t = 0; t <= 128; t++)
    ktile_body<true, 8>(t, lds, A, acc);
  ktile_body<false, 4>(129, lds, A, acc);
  ktile_body<false, 0>(130, lds, A, acc);
  ktile_body<false, -1>(131, lds, A, acc);

  // epilogue: bias + f32 store
#pragma unroll
  for (int n = 0; n < 4; n++) {
    int col = n0 + A.wc * 64 + n * 16 + A.l16;
    float bv = bias[col];
#pragma unroll
    for (int m = 0; m < 8; m++) {
      int row = m0 + A.wr * 128 + m * 16 + lhi * 4;
#pragma unroll
      for (int j = 0; j < 4; j++)
        out[(long)(row + j) * DN + col] = acc[m][n][j] + bv;
    }
  }
}

extern "C" void kernel_launch(void* const* d_in, const int* in_sizes, int n_in,
                              void* d_out, int out_size, void* d_ws, size_t ws_size,
                              hipStream_t stream) {
  const float* x        = (const float*)d_in[0];
  const float* W_base   = (const float*)d_in[1];
  const float* b_base   = (const float*)d_in[2];
  const float* W_router = (const float*)d_in[3];
  const float* b_router = (const float*)d_in[4];
  const float* lora_A   = (const float*)d_in[5];
  const float* lora_B   = (const float*)d_in[6];
  float* out = (float*)d_out;

  char* ws = (char*)d_ws;
  unsigned short* Xb = (unsigned short*)ws;                       // 134217728 B
  unsigned short* Wb = (unsigned short*)(ws + 134217728L);        // 33554432 B
  unsigned short* RA = (unsigned short*)(ws + 167772160L);        // 1310720 B
  unsigned short* BT = (unsigned short*)(ws + 169082880L);        // 1048576 B
  float*          H  = (float*)(ws + 170131456L);                 // 10485760 B
  unsigned short* G  = (unsigned short*)(ws + 180617216L);        // 4194304 B

  hipLaunchKernelGGL(k_cvt, dim3(2048), dim3(256), 0, stream, x, Xb, (long)M_TOK * DK / 4);
  hipLaunchKernelGGL(k_cvt, dim3(2048), dim3(256), 0, stream, W_base, Wb, (long)DN * DK / 4);
  hipLaunchKernelGGL(k_build_ra, dim3((RAC * DK + 255) / 256), dim3(256), 0, stream,
                     W_router, lora_A, RA);
  hipLaunchKernelGGL(k_build_bt, dim3((DN * ERC + 255) / 256), dim3(256), 0, stream, lora_B, BT);
  hipLaunchKernelGGL(k_gemm_small, dim3(M_TOK / 64), dim3(256), 0, stream, Xb, RA, H);
  hipLaunchKernelGGL(k_router, dim3(M_TOK / 256), dim3(256), 0, stream, H, b_router, G);
  hipLaunchKernelGGL(k_gemm_main, dim3((M_TOK / 256) * (DN / 256)), dim3(512), 0, stream,
                     Xb, Wb, G, BT, b_base, out);
}